// Round 4
// baseline (278.410 us; speedup 1.0000x reference)
//
#include <hip/hip_runtime.h>
#include <hip/hip_bf16.h>
#include <math.h>

#define T_DIM 256
#define B_DIM 256
#define H_DIM 512
#define K_DIM 64
#define LN2F 0.69314718055994531f

typedef __attribute__((ext_vector_type(8))) short bfrag_t;  // 8 bf16 (4 VGPRs)
typedef __attribute__((ext_vector_type(4))) float f4_t;     // 4 fp32

// Pack 8 fp32 -> 8 bf16 (RNE) for an MFMA A/B fragment.
__device__ inline bfrag_t pack8(float4 a, float4 b) {
  union { bfrag_t v; __hip_bfloat162 h[4]; } u;
  u.h[0] = __float22bfloat162_rn(float2{a.x, a.y});
  u.h[1] = __float22bfloat162_rn(float2{a.z, a.w});
  u.h[2] = __float22bfloat162_rn(float2{b.x, b.y});
  u.h[3] = __float22bfloat162_rn(float2{b.z, b.w});
  return u.v;
}

// ---------------------------------------------------------------------------
// W pre-convert: fp32 [64][512] -> bf16 (64 KB, L2-resident for the GEMM).
// Also zeroes the output accumulator (replaces the separate memset dispatch;
// runs before crf in stream order, so the atomicAdd target is clean).
// ---------------------------------------------------------------------------
__global__ __launch_bounds__(256) void wconv(const float* __restrict__ W,
                                             short* __restrict__ Wb,
                                             float* __restrict__ out) {
  if (blockIdx.x == 0 && threadIdx.x == 0) *out = 0.f;
  const int i = (blockIdx.x * 256 + threadIdx.x) * 8;
  const float4 a = *(const float4*)(W + i);
  const float4 b = *(const float4*)(W + i + 4);
  *(bfrag_t*)(Wb + i) = pack8(a, b);
}

// ---------------------------------------------------------------------------
// Emission GEMM v9: v8 verified structure (64x64 tile, BK=64, 1-deep A
// prefetch, LDS pad-8 bf16 A-staging, streamed L2 B-frags, 4 blocks/CU,
// raw-score epilogue + gold gather). Change: emP stored as BF16 (8.4 MB vs
// 16.8) — halves emis write traffic and crf's em fetch. DP state y is already
// bf16-truncated every step, so em@bf16 adds comparable-magnitude noise only.
// ---------------------------------------------------------------------------
__global__ __launch_bounds__(256, 4) void emis_gemm9(
    const float* __restrict__ hid,   // [T*B, H]
    const short* __restrict__ Wb,    // [K,H] bf16
    const float* __restrict__ bias,  // [K]
    const int*   __restrict__ tags,  // [T,B]
    short* __restrict__ emPb,        // [16,256,64,16] bf16 (permuted exp scores)
    float* __restrict__ goldRaw)     // [T,B] raw score at gold tag (fp32)
{
  __shared__ __hip_bfloat16 AsH[2][64 * 72];     // 2 x 9216 B
  float* Cs = (float*)&AsH[0][0];                // epilogue reuse (17408 B <= 18432)

  const int tid  = threadIdx.x;
  const int wv   = tid >> 6;
  const int lane = tid & 63;
  const int l16  = lane & 15;
  const int quad = lane >> 4;
  const int m0   = blockIdx.x * 64;   // 64 consecutive m = t fixed, b in [b0,b0+64)

  // per-lane B-frag base: row j = wv*16+l16, k-offset quad*8 (shorts)
  const short* wb = Wb + ((wv * 16 + l16) * H_DIM + quad * 8);

  // Staging: thread -> row sr = tid>>2 (64 rows), k-segment sc = (tid&3)*16.
  const int sr = tid >> 2;
  const int sc = (tid & 3) << 4;
  const float* hrow = hid + (size_t)(m0 + sr) * H_DIM + sc;

  f4_t acc[4];
#pragma unroll
  for (int mt = 0; mt < 4; ++mt) acc[mt] = (f4_t){0.f, 0.f, 0.f, 0.f};

  float4 p0 = *(const float4*)(hrow + 0);
  float4 p1 = *(const float4*)(hrow + 4);
  float4 p2 = *(const float4*)(hrow + 8);
  float4 p3 = *(const float4*)(hrow + 12);
  bfrag_t bc0 = *(const bfrag_t*)(wb + 0);    // it=0, kc2=0
  bfrag_t bc1 = *(const bfrag_t*)(wb + 32);   // it=0, kc2=1
  *(bfrag_t*)(&AsH[0][sr * 72 + sc + 0]) = pack8(p0, p1);
  *(bfrag_t*)(&AsH[0][sr * 72 + sc + 8]) = pack8(p2, p3);
  __syncthreads();

#pragma unroll
  for (int it = 0; it < 8; ++it) {
    bfrag_t bn0, bn1;
    if (it < 7) {
      p0 = *(const float4*)(hrow + (it + 1) * 64 + 0);
      p1 = *(const float4*)(hrow + (it + 1) * 64 + 4);
      p2 = *(const float4*)(hrow + (it + 1) * 64 + 8);
      p3 = *(const float4*)(hrow + (it + 1) * 64 + 12);
      bn0 = *(const bfrag_t*)(wb + (it + 1) * 64);        // (it+1,kc2=0)
      bn1 = *(const bfrag_t*)(wb + (it + 1) * 64 + 32);   // (it+1,kc2=1)
    }
#pragma unroll
    for (int kc2 = 0; kc2 < 2; ++kc2) {
      const bfrag_t bf = kc2 ? bc1 : bc0;
#pragma unroll
      for (int mt = 0; mt < 4; ++mt) {
        const bfrag_t af =
            *(const bfrag_t*)(&AsH[it & 1][(mt * 16 + l16) * 72 + kc2 * 32 + quad * 8]);
        acc[mt] = __builtin_amdgcn_mfma_f32_16x16x32_bf16(af, bf, acc[mt], 0, 0, 0);
      }
    }
    if (it < 7) {
      *(bfrag_t*)(&AsH[(it + 1) & 1][sr * 72 + sc + 0]) = pack8(p0, p1);
      *(bfrag_t*)(&AsH[(it + 1) & 1][sr * 72 + sc + 8]) = pack8(p2, p3);
      bc0 = bn0; bc1 = bn1;
    }
    __syncthreads();
  }

  // ---- epilogue: RAW scores -> LDS [m][j] (stride 68); gold gather (fp32);
  // exp + bf16 pack at the permuted coalesced store (each lane: 32 B contig).
  const float bn = bias[wv * 16 + l16];
#pragma unroll
  for (int mt = 0; mt < 4; ++mt)
#pragma unroll
    for (int r = 0; r < 4; ++r)
      Cs[(mt * 16 + quad * 4 + r) * 68 + wv * 16 + l16] = acc[mt][r] + bn;
  __syncthreads();

  const int t  = m0 >> 8;
  const int b0 = m0 & 255;
  if (tid < 64) {
    const int tg = tags[t * B_DIM + b0 + tid];
    goldRaw[t * B_DIM + b0 + tid] = Cs[tid * 68 + tg];
  }

  const int g0 = b0 >> 4;
  const int bl = tid & 15;
  const int qq = (tid >> 4) & 3;
  const int gl = tid >> 6;
#pragma unroll
  for (int i2 = 0; i2 < 2; ++i2) {
    float4 v0 = *(const float4*)(&Cs[(gl * 16 + bl) * 68 + (i2 * 2 + 0) * 16 + qq * 4]);
    float4 v1 = *(const float4*)(&Cs[(gl * 16 + bl) * 68 + (i2 * 2 + 1) * 16 + qq * 4]);
    v0.x = __expf(v0.x); v0.y = __expf(v0.y); v0.z = __expf(v0.z); v0.w = __expf(v0.w);
    v1.x = __expf(v1.x); v1.y = __expf(v1.y); v1.z = __expf(v1.z); v1.w = __expf(v1.w);
    const size_t off = ((((size_t)(g0 + gl) * 256 + t) * 64 + qq * 16 + bl) << 4) + i2 * 8;
    *(bfrag_t*)(emPb + off) = pack8(v0, v1);
  }
}

// ---------------------------------------------------------------------------
// CRF DP v9 == v8 structure (fwd/bwd meet-in-middle, 8-deep reg prefetch
// ring, chained-MFMA step, balanced rescale tree, gold from fp32 side
// channel). Change: em loaded as bf16 (2x16B per LOADW instead of 4x16B),
// converted to fp32 at load time (off the dependent MFMA chain).
// ---------------------------------------------------------------------------
__global__ __launch_bounds__(128) void crf_dp9(
    const short* __restrict__ emPb,
    const float* __restrict__ goldRaw,
    const int* __restrict__ lens,
    const int* __restrict__ tags,
    const float* __restrict__ trans,
    const float* __restrict__ beginT,
    const float* __restrict__ endT,
    float* __restrict__ out)
{
  const int g    = blockIdx.x;
  const int tid  = threadIdx.x;
  const int wv   = tid >> 6;     // 0 = forward, 1 = backward
  const int lane = tid & 63;
  const int n    = lane & 15;
  const int q    = lane >> 4;
  const int b    = g * 16 + n;

  __shared__ float xs[64 * 16];  // x_127 per fwd-lane
  __shared__ int   Lxs[64];
  __shared__ float s0d[16];      // snap·eend per column
  __shared__ int   Ls0[16];
  __shared__ float gpart;        // wave0 gold partial

  const int len = lens[b];
  const int cap = len - 1;
  const short* base = emPb + (((size_t)g * 256) * 64 + lane) * 16;

  float eend[16];
#pragma unroll
  for (int k = 0; k < 16; ++k)
    eend[k] = __expf(endT[(k >> 2) * 16 + q * 4 + (k & 3)]);

  float y[16];
  int Lint = 0;
  bfrag_t bf0, bf1;
  float wA[16], wB[16], wC[16], wD[16], wE[16], wF[16], wG[16], wH[16];
  float g0 = 0.f;   // per-lane gold partial (this wave's t-range)

#define LOADW(dst, t) { \
    union { bfrag_t v; __hip_bfloat162 h[4]; } _u0, _u1; \
    _u0.v = *(const bfrag_t*)(base + (size_t)(t) * 1024 + 0); \
    _u1.v = *(const bfrag_t*)(base + (size_t)(t) * 1024 + 8); \
    float2 _f; \
    _f = __bfloat1622float2(_u0.h[0]); dst[0] = _f.x; dst[1] = _f.y; \
    _f = __bfloat1622float2(_u0.h[1]); dst[2] = _f.x; dst[3] = _f.y; \
    _f = __bfloat1622float2(_u0.h[2]); dst[4] = _f.x; dst[5] = _f.y; \
    _f = __bfloat1622float2(_u0.h[3]); dst[6] = _f.x; dst[7] = _f.y; \
    _f = __bfloat1622float2(_u1.h[0]); dst[8] = _f.x; dst[9] = _f.y; \
    _f = __bfloat1622float2(_u1.h[1]); dst[10] = _f.x; dst[11] = _f.y; \
    _f = __bfloat1622float2(_u1.h[2]); dst[12] = _f.x; dst[13] = _f.y; \
    _f = __bfloat1622float2(_u1.h[3]); dst[14] = _f.x; dst[15] = _f.y; }

  // balanced max tree: depth 4 instead of serial depth 15 (bit-identical)
#define RESCALE() { \
    float _m0 = fmaxf(fmaxf(y[0], y[1]), fmaxf(y[2], y[3])); \
    float _m1 = fmaxf(fmaxf(y[4], y[5]), fmaxf(y[6], y[7])); \
    float _m2 = fmaxf(fmaxf(y[8], y[9]), fmaxf(y[10], y[11])); \
    float _m3 = fmaxf(fmaxf(y[12], y[13]), fmaxf(y[14], y[15])); \
    float _mx = fmaxf(fmaxf(_m0, _m1), fmaxf(_m2, _m3)); \
    _mx = fmaxf(_mx, __shfl_xor(_mx, 16)); \
    _mx = fmaxf(_mx, __shfl_xor(_mx, 32)); \
    int _e; (void)frexpf(_mx, &_e); \
    Lint += _e; \
    _Pragma("unroll") for (int k = 0; k < 16; ++k) y[k] = ldexpf(y[k], -_e); }

#define BUILDBV(S) { \
    union { bfrag_t v; __hip_bfloat162 h[4]; } _u0, _u1; \
    _u0.h[0] = __float22bfloat162_rn(float2{S[0], S[1]}); \
    _u0.h[1] = __float22bfloat162_rn(float2{S[2], S[3]}); \
    _u0.h[2] = __float22bfloat162_rn(float2{S[4], S[5]}); \
    _u0.h[3] = __float22bfloat162_rn(float2{S[6], S[7]}); \
    _u1.h[0] = __float22bfloat162_rn(float2{S[8], S[9]}); \
    _u1.h[1] = __float22bfloat162_rn(float2{S[10], S[11]}); \
    _u1.h[2] = __float22bfloat162_rn(float2{S[12], S[13]}); \
    _u1.h[3] = __float22bfloat162_rn(float2{S[14], S[15]}); \
    bf0 = _u0.v; bf1 = _u1.v; }

  const f4_t zro = (f4_t){0.f, 0.f, 0.f, 0.f};

  if (wv == 0) {
    // ---- forward wave ----
    bfrag_t aE[8];
#pragma unroll
    for (int jt = 0; jt < 4; ++jt)
#pragma unroll
      for (int kt = 0; kt < 2; ++kt) {
        union { bfrag_t v; __hip_bfloat16 h[8]; } u;
#pragma unroll
        for (int r = 0; r < 8; ++r) {
          const int i = (2 * kt + (r >> 2)) * 16 + q * 4 + (r & 3);
          u.h[r] = __float2bfloat16(__expf(trans[(jt * 16 + n) * K_DIM + i]));
        }
        aE[jt * 2 + kt] = u.v;
      }

    float snap[16];
    int Lsnap = 0;
    LOADW(wA, 0);
#pragma unroll
    for (int k = 0; k < 16; ++k) {
      const int j = (k >> 2) * 16 + q * 4 + (k & 3);
      y[k] = wA[k] * __expf(beginT[j]);
      snap[k] = (cap == 0) ? y[k] : 0.0f;
    }
    RESCALE(); BUILDBV(y);
    LOADW(wA, 1); LOADW(wB, 2); LOADW(wC, 3); LOADW(wD, 4);
    LOADW(wE, 5); LOADW(wF, 6); LOADW(wG, 7); LOADW(wH, 8);

#define STEPF(T, W, RSC) { \
    f4_t _a0 = __builtin_amdgcn_mfma_f32_16x16x32_bf16(aE[0], bf0, zro, 0, 0, 0); \
    f4_t _a1 = __builtin_amdgcn_mfma_f32_16x16x32_bf16(aE[2], bf0, zro, 0, 0, 0); \
    f4_t _a2 = __builtin_amdgcn_mfma_f32_16x16x32_bf16(aE[4], bf0, zro, 0, 0, 0); \
    f4_t _a3 = __builtin_amdgcn_mfma_f32_16x16x32_bf16(aE[6], bf0, zro, 0, 0, 0); \
    _a0 = __builtin_amdgcn_mfma_f32_16x16x32_bf16(aE[1], bf1, _a0, 0, 0, 0); \
    _a1 = __builtin_amdgcn_mfma_f32_16x16x32_bf16(aE[3], bf1, _a1, 0, 0, 0); \
    _a2 = __builtin_amdgcn_mfma_f32_16x16x32_bf16(aE[5], bf1, _a2, 0, 0, 0); \
    _a3 = __builtin_amdgcn_mfma_f32_16x16x32_bf16(aE[7], bf1, _a3, 0, 0, 0); \
    _Pragma("unroll") for (int r = 0; r < 4; ++r) { \
      y[r]      = _a0[r] * W[r]; \
      y[4 + r]  = _a1[r] * W[4 + r]; \
      y[8 + r]  = _a2[r] * W[8 + r]; \
      y[12 + r] = _a3[r] * W[12 + r]; } \
    const bool _hit = ((T) == cap); \
    _Pragma("unroll") for (int k = 0; k < 16; ++k) snap[k] = _hit ? y[k] : snap[k]; \
    Lsnap = _hit ? Lint : Lsnap; \
    if (RSC) { RESCALE(); } \
    BUILDBV(y); }

    int t = 1;
    for (int it = 0; it < 15; ++it, t += 8) {
      STEPF(t + 0, wA, 0); LOADW(wA, t + 8);
      STEPF(t + 1, wB, 0); LOADW(wB, t + 9);
      STEPF(t + 2, wC, 1); LOADW(wC, t + 10);
      STEPF(t + 3, wD, 0); LOADW(wD, t + 11);
      STEPF(t + 4, wE, 0); LOADW(wE, t + 12);
      STEPF(t + 5, wF, 0); LOADW(wF, t + 13);
      STEPF(t + 6, wG, 1); LOADW(wG, t + 14);
      STEPF(t + 7, wH, 0); LOADW(wH, t + 15);
    }
    // tail: t = 121..127
    STEPF(121, wA, 0); STEPF(122, wB, 0); STEPF(123, wC, 1); STEPF(124, wD, 0);
    STEPF(125, wE, 0); STEPF(126, wF, 0); STEPF(127, wG, 0);

    // publish x_127 / scales / snap-dot
#pragma unroll
    for (int k = 0; k < 16; ++k) xs[lane * 16 + k] = y[k];
    Lxs[lane] = Lint;
    float sd = 0.f;
#pragma unroll
    for (int k = 0; k < 16; ++k) sd += snap[k] * eend[k];
    sd += __shfl_xor(sd, 16);
    sd += __shfl_xor(sd, 32);
    if (lane < 16) { s0d[lane] = sd; Ls0[lane] = Lsnap; }

    // gold partial: t in [0,128) — raw fp32 scores from the side channel
    for (int c = 0; c < 32; ++c) {
      const int tt = q + 4 * c;
      if (tt < len) {
        const int tg = tags[(size_t)tt * B_DIM + b];
        float v = goldRaw[(size_t)tt * B_DIM + b];
        v += (tt == 0) ? beginT[tg]
                       : trans[(size_t)tg * K_DIM + tags[(size_t)(tt - 1) * B_DIM + b]];
        if (tt == cap) v += endT[tg];
        g0 += v;
      }
    }
    float gr = g0;
#pragma unroll
    for (int o = 1; o < 64; o <<= 1) gr += __shfl_xor(gr, o);
    if (lane == 0) gpart = gr;
  } else {
    // ---- backward wave ----
    bfrag_t aET[8];
#pragma unroll
    for (int jt = 0; jt < 4; ++jt)
#pragma unroll
      for (int kt = 0; kt < 2; ++kt) {
        union { bfrag_t v; __hip_bfloat16 h[8]; } u;
#pragma unroll
        for (int r = 0; r < 8; ++r) {
          const int i = (2 * kt + (r >> 2)) * 16 + q * 4 + (r & 3);
          u.h[r] = __float2bfloat16(__expf(trans[(size_t)i * K_DIM + (jt * 16 + n)]));
        }
        aET[jt * 2 + kt] = u.v;
      }

#pragma unroll
    for (int k = 0; k < 16; ++k) y[k] = 0.f;
    LOADW(wA, 255); LOADW(wB, 254); LOADW(wC, 253); LOADW(wD, 252);
    LOADW(wE, 251); LOADW(wF, 250); LOADW(wG, 249); LOADW(wH, 248);

#define STEPB(T, W, RSC) { \
    const bool _hit = ((T) == cap); \
    float _d[16]; \
    _Pragma("unroll") for (int k = 0; k < 16; ++k) \
      _d[k] = (_hit ? eend[k] : y[k]) * W[k]; \
    BUILDBV(_d); \
    f4_t _a0 = __builtin_amdgcn_mfma_f32_16x16x32_bf16(aET[0], bf0, zro, 0, 0, 0); \
    f4_t _a1 = __builtin_amdgcn_mfma_f32_16x16x32_bf16(aET[2], bf0, zro, 0, 0, 0); \
    f4_t _a2 = __builtin_amdgcn_mfma_f32_16x16x32_bf16(aET[4], bf0, zro, 0, 0, 0); \
    f4_t _a3 = __builtin_amdgcn_mfma_f32_16x16x32_bf16(aET[6], bf0, zro, 0, 0, 0); \
    _a0 = __builtin_amdgcn_mfma_f32_16x16x32_bf16(aET[1], bf1, _a0, 0, 0, 0); \
    _a1 = __builtin_amdgcn_mfma_f32_16x16x32_bf16(aET[3], bf1, _a1, 0, 0, 0); \
    _a2 = __builtin_amdgcn_mfma_f32_16x16x32_bf16(aET[5], bf1, _a2, 0, 0, 0); \
    _a3 = __builtin_amdgcn_mfma_f32_16x16x32_bf16(aET[7], bf1, _a3, 0, 0, 0); \
    _Pragma("unroll") for (int r = 0; r < 4; ++r) { \
      y[r]      = _a0[r]; \
      y[4 + r]  = _a1[r]; \
      y[8 + r]  = _a2[r]; \
      y[12 + r] = _a3[r]; } \
    if (RSC) { RESCALE(); } }

    int t = 255;
    for (int it = 0; it < 16; ++it, t -= 8) {
      STEPB(t - 0, wA, 0); LOADW(wA, t - 8);
      STEPB(t - 1, wB, 0); LOADW(wB, t - 9);
      STEPB(t - 2, wC, 1); LOADW(wC, t - 10);
      STEPB(t - 3, wD, 0); LOADW(wD, t - 11);
      STEPB(t - 4, wE, 0); LOADW(wE, t - 12);
      STEPB(t - 5, wF, 0); LOADW(wF, t - 13);
      STEPB(t - 6, wG, 1); LOADW(wG, t - 14);
      STEPB(t - 7, wH, 0); LOADW(wH, t - 15);
    }
    // y = u_127 (scale Lint = Lu)

    // gold partial: t in [128,256) — raw fp32 scores from the side channel
    for (int c = 0; c < 32; ++c) {
      const int tt = 128 + q + 4 * c;
      if (tt < len) {
        const int tg = tags[(size_t)tt * B_DIM + b];
        float v = goldRaw[(size_t)tt * B_DIM + b];
        v += trans[(size_t)tg * K_DIM + tags[(size_t)(tt - 1) * B_DIM + b]];
        if (tt == cap) v += endT[tg];
        g0 += v;
      }
    }
  }

  __syncthreads();

  if (wv == 1) {
    float dot1 = 0.f;
#pragma unroll
    for (int k = 0; k < 16; ++k) dot1 += xs[lane * 16 + k] * y[k];
    dot1 += __shfl_xor(dot1, 16);
    dot1 += __shfl_xor(dot1, 32);

    const bool hi = (cap >= 128);
    const float dsel = hi ? dot1 : s0d[n];
    const float Lsel = (float)(hi ? (Lxs[lane] + Lint) : Ls0[n]);
    const float f = __logf(dsel) + Lsel * LN2F;

    float r = 0.25f * f - g0;
#pragma unroll
    for (int o = 1; o < 64; o <<= 1) r += __shfl_xor(r, o);
    if (lane == 0) atomicAdd(out, r - gpart);
  }
}

// ---------------------------------------------------------------------------
extern "C" void kernel_launch(void* const* d_in, const int* in_sizes, int n_in,
                              void* d_out, int out_size, void* d_ws, size_t ws_size,
                              hipStream_t stream) {
  const float* hiddens = (const float*)d_in[0];  // [T,B,H]
  const int*   lens    = (const int*)  d_in[1];  // [B]
  const int*   tags    = (const int*)  d_in[2];  // [T,B]
  const float* W       = (const float*)d_in[3];  // [K,H]
  const float* bias    = (const float*)d_in[4];  // [K]
  const float* beginT  = (const float*)d_in[5];  // [K]
  const float* trans   = (const float*)d_in[6];  // [K,K]
  const float* endT    = (const float*)d_in[7];  // [K]

  short* emPb    = (short*)d_ws;                            // 8.4 MB bf16
  float* goldRaw = (float*)(emPb + (size_t)16 * 256 * 64 * 16);  // 256 KB
  short* Wb      = (short*)(goldRaw + B_DIM * T_DIM);       // 64 KB bf16
  float* out     = (float*)d_out;

  wconv<<<(K_DIM * H_DIM) / (256 * 8), 256, 0, stream>>>(W, Wb, out);
  emis_gemm9<<<(T_DIM * B_DIM) / 64, 256, 0, stream>>>(hiddens, Wb, bias, tags, emPb, goldRaw);
  crf_dp9<<<16, 128, 0, stream>>>(emPb, goldRaw, lens, tags, trans, beginT, endT, out);
}

// Round 5
// 253.132 us; speedup vs baseline: 1.0999x; 1.0999x over previous
//
#include <hip/hip_runtime.h>
#include <hip/hip_bf16.h>
#include <math.h>

#define T_DIM 256
#define B_DIM 256
#define H_DIM 512
#define K_DIM 64
#define LN2F 0.69314718055994531f

typedef __attribute__((ext_vector_type(8))) short bfrag_t;  // 8 bf16 (4 VGPRs)
typedef __attribute__((ext_vector_type(4))) float f4_t;     // 4 fp32

// Pack 8 fp32 -> 8 bf16 (RNE) for an MFMA A/B fragment.
__device__ inline bfrag_t pack8(float4 a, float4 b) {
  union { bfrag_t v; __hip_bfloat162 h[4]; } u;
  u.h[0] = __float22bfloat162_rn(float2{a.x, a.y});
  u.h[1] = __float22bfloat162_rn(float2{a.z, a.w});
  u.h[2] = __float22bfloat162_rn(float2{b.x, b.y});
  u.h[3] = __float22bfloat162_rn(float2{b.z, b.w});
  return u.v;
}

// ---------------------------------------------------------------------------
// W pre-convert: fp32 [64][512] -> bf16 (64 KB, L2-resident for the GEMM).
// Also zeroes the output accumulator (replaces the separate memset dispatch).
// ---------------------------------------------------------------------------
__global__ __launch_bounds__(256) void wconv(const float* __restrict__ W,
                                             short* __restrict__ Wb,
                                             float* __restrict__ out) {
  if (blockIdx.x == 0 && threadIdx.x == 0) *out = 0.f;
  const int i = (blockIdx.x * 256 + threadIdx.x) * 8;
  const float4 a = *(const float4*)(W + i);
  const float4 b = *(const float4*)(W + i + 4);
  *(bfrag_t*)(Wb + i) = pack8(a, b);
}

// ---------------------------------------------------------------------------
// Emission GEMM v10 == v9 (verified): 64x64 tile, BK=64, 1-deep A prefetch,
// LDS pad-8 bf16 A-staging, streamed L2 B-frags, 4 blocks/CU, raw-score
// epilogue + fp32 gold gather, bf16 emP output (8.4 MB).
// ---------------------------------------------------------------------------
__global__ __launch_bounds__(256, 4) void emis_gemm10(
    const float* __restrict__ hid,   // [T*B, H]
    const short* __restrict__ Wb,    // [K,H] bf16
    const float* __restrict__ bias,  // [K]
    const int*   __restrict__ tags,  // [T,B]
    short* __restrict__ emPb,        // [16,256,64,16] bf16 (permuted exp scores)
    float* __restrict__ goldRaw)     // [T,B] raw score at gold tag (fp32)
{
  __shared__ __hip_bfloat16 AsH[2][64 * 72];     // 2 x 9216 B
  float* Cs = (float*)&AsH[0][0];                // epilogue reuse (17408 B <= 18432)

  const int tid  = threadIdx.x;
  const int wv   = tid >> 6;
  const int lane = tid & 63;
  const int l16  = lane & 15;
  const int quad = lane >> 4;
  const int m0   = blockIdx.x * 64;   // 64 consecutive m = t fixed, b in [b0,b0+64)

  const short* wb = Wb + ((wv * 16 + l16) * H_DIM + quad * 8);

  const int sr = tid >> 2;
  const int sc = (tid & 3) << 4;
  const float* hrow = hid + (size_t)(m0 + sr) * H_DIM + sc;

  f4_t acc[4];
#pragma unroll
  for (int mt = 0; mt < 4; ++mt) acc[mt] = (f4_t){0.f, 0.f, 0.f, 0.f};

  float4 p0 = *(const float4*)(hrow + 0);
  float4 p1 = *(const float4*)(hrow + 4);
  float4 p2 = *(const float4*)(hrow + 8);
  float4 p3 = *(const float4*)(hrow + 12);
  bfrag_t bc0 = *(const bfrag_t*)(wb + 0);
  bfrag_t bc1 = *(const bfrag_t*)(wb + 32);
  *(bfrag_t*)(&AsH[0][sr * 72 + sc + 0]) = pack8(p0, p1);
  *(bfrag_t*)(&AsH[0][sr * 72 + sc + 8]) = pack8(p2, p3);
  __syncthreads();

#pragma unroll
  for (int it = 0; it < 8; ++it) {
    bfrag_t bn0, bn1;
    if (it < 7) {
      p0 = *(const float4*)(hrow + (it + 1) * 64 + 0);
      p1 = *(const float4*)(hrow + (it + 1) * 64 + 4);
      p2 = *(const float4*)(hrow + (it + 1) * 64 + 8);
      p3 = *(const float4*)(hrow + (it + 1) * 64 + 12);
      bn0 = *(const bfrag_t*)(wb + (it + 1) * 64);
      bn1 = *(const bfrag_t*)(wb + (it + 1) * 64 + 32);
    }
#pragma unroll
    for (int kc2 = 0; kc2 < 2; ++kc2) {
      const bfrag_t bf = kc2 ? bc1 : bc0;
#pragma unroll
      for (int mt = 0; mt < 4; ++mt) {
        const bfrag_t af =
            *(const bfrag_t*)(&AsH[it & 1][(mt * 16 + l16) * 72 + kc2 * 32 + quad * 8]);
        acc[mt] = __builtin_amdgcn_mfma_f32_16x16x32_bf16(af, bf, acc[mt], 0, 0, 0);
      }
    }
    if (it < 7) {
      *(bfrag_t*)(&AsH[(it + 1) & 1][sr * 72 + sc + 0]) = pack8(p0, p1);
      *(bfrag_t*)(&AsH[(it + 1) & 1][sr * 72 + sc + 8]) = pack8(p2, p3);
      bc0 = bn0; bc1 = bn1;
    }
    __syncthreads();
  }

  const float bn = bias[wv * 16 + l16];
#pragma unroll
  for (int mt = 0; mt < 4; ++mt)
#pragma unroll
    for (int r = 0; r < 4; ++r)
      Cs[(mt * 16 + quad * 4 + r) * 68 + wv * 16 + l16] = acc[mt][r] + bn;
  __syncthreads();

  const int t  = m0 >> 8;
  const int b0 = m0 & 255;
  if (tid < 64) {
    const int tg = tags[t * B_DIM + b0 + tid];
    goldRaw[t * B_DIM + b0 + tid] = Cs[tid * 68 + tg];
  }

  const int g0 = b0 >> 4;
  const int bl = tid & 15;
  const int qq = (tid >> 4) & 3;
  const int gl = tid >> 6;
#pragma unroll
  for (int i2 = 0; i2 < 2; ++i2) {
    float4 v0 = *(const float4*)(&Cs[(gl * 16 + bl) * 68 + (i2 * 2 + 0) * 16 + qq * 4]);
    float4 v1 = *(const float4*)(&Cs[(gl * 16 + bl) * 68 + (i2 * 2 + 1) * 16 + qq * 4]);
    v0.x = __expf(v0.x); v0.y = __expf(v0.y); v0.z = __expf(v0.z); v0.w = __expf(v0.w);
    v1.x = __expf(v1.x); v1.y = __expf(v1.y); v1.z = __expf(v1.z); v1.w = __expf(v1.w);
    const size_t off = ((((size_t)(g0 + gl) * 256 + t) * 64 + qq * 16 + bl) << 4) + i2 * 8;
    *(bfrag_t*)(emPb + off) = pack8(v0, v1);
  }
}

// ---------------------------------------------------------------------------
// CRF DP v10: ANTI-SPILL rebuild. R4 exposed VGPR_Count=140 vs ~240 live ->
// the fp32 prefetch ring has been spilling to scratch every step (the hidden
// ~1300cy/step stall; crf was 76-94us vs ~8us of arithmetic).
//  (a) __launch_bounds__(128, 1): allocator budget up to 512 VGPR/wave.
//  (b) ring kept in RAW BF16 (16 named bfrag_t = 64 VGPR, was 128 fp32),
//      converted to fp32 at USE (cvts depend on 8-step-old data; hide under
//      MFMA latency). Numerically identical to v9.
// ---------------------------------------------------------------------------
__global__ __launch_bounds__(128, 1) void crf_dp10(
    const short* __restrict__ emPb,
    const float* __restrict__ goldRaw,
    const int* __restrict__ lens,
    const int* __restrict__ tags,
    const float* __restrict__ trans,
    const float* __restrict__ beginT,
    const float* __restrict__ endT,
    float* __restrict__ out)
{
  const int g    = blockIdx.x;
  const int tid  = threadIdx.x;
  const int wv   = tid >> 6;     // 0 = forward, 1 = backward
  const int lane = tid & 63;
  const int n    = lane & 15;
  const int q    = lane >> 4;
  const int b    = g * 16 + n;

  __shared__ float xs[64 * 16];  // x_127 per fwd-lane
  __shared__ int   Lxs[64];
  __shared__ float s0d[16];      // snap·eend per column
  __shared__ int   Ls0[16];
  __shared__ float gpart;        // wave0 gold partial

  const int len = lens[b];
  const int cap = len - 1;
  const short* base = emPb + (((size_t)g * 256) * 64 + lane) * 16;

  float eend[16];
#pragma unroll
  for (int k = 0; k < 16; ++k)
    eend[k] = __expf(endT[(k >> 2) * 16 + q * 4 + (k & 3)]);

  float y[16];
  int Lint = 0;
  bfrag_t bf0, bf1;
  // bf16 prefetch ring: 8 slots x 2 bfrag_t = 64 VGPR
  bfrag_t wA0, wA1, wB0, wB1, wC0, wC1, wD0, wD1;
  bfrag_t wE0, wE1, wF0, wF1, wG0, wG1, wH0, wH1;
  float g0 = 0.f;   // per-lane gold partial (this wave's t-range)

// pure loads, no conversion -> nothing forces an early vmcnt wait
#define LOADW(D0, D1, t) { \
    D0 = *(const bfrag_t*)(base + (size_t)(t) * 1024 + 0); \
    D1 = *(const bfrag_t*)(base + (size_t)(t) * 1024 + 8); }

// bf16x16 -> fp32x16 at use time (data is 8 steps old; cvts schedule freely)
#define CVT16(DST, S0, S1) { \
    union { bfrag_t v; __hip_bfloat162 h[4]; } _c0, _c1; \
    _c0.v = (S0); _c1.v = (S1); \
    float2 _f; \
    _f = __bfloat1622float2(_c0.h[0]); DST[0] = _f.x; DST[1] = _f.y; \
    _f = __bfloat1622float2(_c0.h[1]); DST[2] = _f.x; DST[3] = _f.y; \
    _f = __bfloat1622float2(_c0.h[2]); DST[4] = _f.x; DST[5] = _f.y; \
    _f = __bfloat1622float2(_c0.h[3]); DST[6] = _f.x; DST[7] = _f.y; \
    _f = __bfloat1622float2(_c1.h[0]); DST[8] = _f.x; DST[9] = _f.y; \
    _f = __bfloat1622float2(_c1.h[1]); DST[10] = _f.x; DST[11] = _f.y; \
    _f = __bfloat1622float2(_c1.h[2]); DST[12] = _f.x; DST[13] = _f.y; \
    _f = __bfloat1622float2(_c1.h[3]); DST[14] = _f.x; DST[15] = _f.y; }

  // balanced max tree: depth 4 (bit-identical)
#define RESCALE() { \
    float _m0 = fmaxf(fmaxf(y[0], y[1]), fmaxf(y[2], y[3])); \
    float _m1 = fmaxf(fmaxf(y[4], y[5]), fmaxf(y[6], y[7])); \
    float _m2 = fmaxf(fmaxf(y[8], y[9]), fmaxf(y[10], y[11])); \
    float _m3 = fmaxf(fmaxf(y[12], y[13]), fmaxf(y[14], y[15])); \
    float _mx = fmaxf(fmaxf(_m0, _m1), fmaxf(_m2, _m3)); \
    _mx = fmaxf(_mx, __shfl_xor(_mx, 16)); \
    _mx = fmaxf(_mx, __shfl_xor(_mx, 32)); \
    int _e; (void)frexpf(_mx, &_e); \
    Lint += _e; \
    _Pragma("unroll") for (int k = 0; k < 16; ++k) y[k] = ldexpf(y[k], -_e); }

#define BUILDBV(S) { \
    union { bfrag_t v; __hip_bfloat162 h[4]; } _u0, _u1; \
    _u0.h[0] = __float22bfloat162_rn(float2{S[0], S[1]}); \
    _u0.h[1] = __float22bfloat162_rn(float2{S[2], S[3]}); \
    _u0.h[2] = __float22bfloat162_rn(float2{S[4], S[5]}); \
    _u0.h[3] = __float22bfloat162_rn(float2{S[6], S[7]}); \
    _u1.h[0] = __float22bfloat162_rn(float2{S[8], S[9]}); \
    _u1.h[1] = __float22bfloat162_rn(float2{S[10], S[11]}); \
    _u1.h[2] = __float22bfloat162_rn(float2{S[12], S[13]}); \
    _u1.h[3] = __float22bfloat162_rn(float2{S[14], S[15]}); \
    bf0 = _u0.v; bf1 = _u1.v; }

  const f4_t zro = (f4_t){0.f, 0.f, 0.f, 0.f};

  if (wv == 0) {
    // ---- forward wave ----
    bfrag_t aE[8];
#pragma unroll
    for (int jt = 0; jt < 4; ++jt)
#pragma unroll
      for (int kt = 0; kt < 2; ++kt) {
        union { bfrag_t v; __hip_bfloat16 h[8]; } u;
#pragma unroll
        for (int r = 0; r < 8; ++r) {
          const int i = (2 * kt + (r >> 2)) * 16 + q * 4 + (r & 3);
          u.h[r] = __float2bfloat16(__expf(trans[(jt * 16 + n) * K_DIM + i]));
        }
        aE[jt * 2 + kt] = u.v;
      }

    float snap[16];
    int Lsnap = 0;
    LOADW(wA0, wA1, 0);
    {
      float w0[16];
      CVT16(w0, wA0, wA1);
#pragma unroll
      for (int k = 0; k < 16; ++k) {
        const int j = (k >> 2) * 16 + q * 4 + (k & 3);
        y[k] = w0[k] * __expf(beginT[j]);
        snap[k] = (cap == 0) ? y[k] : 0.0f;
      }
    }
    RESCALE(); BUILDBV(y);
    LOADW(wA0, wA1, 1); LOADW(wB0, wB1, 2); LOADW(wC0, wC1, 3); LOADW(wD0, wD1, 4);
    LOADW(wE0, wE1, 5); LOADW(wF0, wF1, 6); LOADW(wG0, wG1, 7); LOADW(wH0, wH1, 8);

#define STEPF(T, W0, W1, RSC) { \
    float _w[16]; \
    CVT16(_w, W0, W1); \
    f4_t _a0 = __builtin_amdgcn_mfma_f32_16x16x32_bf16(aE[0], bf0, zro, 0, 0, 0); \
    f4_t _a1 = __builtin_amdgcn_mfma_f32_16x16x32_bf16(aE[2], bf0, zro, 0, 0, 0); \
    f4_t _a2 = __builtin_amdgcn_mfma_f32_16x16x32_bf16(aE[4], bf0, zro, 0, 0, 0); \
    f4_t _a3 = __builtin_amdgcn_mfma_f32_16x16x32_bf16(aE[6], bf0, zro, 0, 0, 0); \
    _a0 = __builtin_amdgcn_mfma_f32_16x16x32_bf16(aE[1], bf1, _a0, 0, 0, 0); \
    _a1 = __builtin_amdgcn_mfma_f32_16x16x32_bf16(aE[3], bf1, _a1, 0, 0, 0); \
    _a2 = __builtin_amdgcn_mfma_f32_16x16x32_bf16(aE[5], bf1, _a2, 0, 0, 0); \
    _a3 = __builtin_amdgcn_mfma_f32_16x16x32_bf16(aE[7], bf1, _a3, 0, 0, 0); \
    _Pragma("unroll") for (int r = 0; r < 4; ++r) { \
      y[r]      = _a0[r] * _w[r]; \
      y[4 + r]  = _a1[r] * _w[4 + r]; \
      y[8 + r]  = _a2[r] * _w[8 + r]; \
      y[12 + r] = _a3[r] * _w[12 + r]; } \
    const bool _hit = ((T) == cap); \
    _Pragma("unroll") for (int k = 0; k < 16; ++k) snap[k] = _hit ? y[k] : snap[k]; \
    Lsnap = _hit ? Lint : Lsnap; \
    if (RSC) { RESCALE(); } \
    BUILDBV(y); }

    int t = 1;
    for (int it = 0; it < 15; ++it, t += 8) {
      STEPF(t + 0, wA0, wA1, 0); LOADW(wA0, wA1, t + 8);
      STEPF(t + 1, wB0, wB1, 0); LOADW(wB0, wB1, t + 9);
      STEPF(t + 2, wC0, wC1, 1); LOADW(wC0, wC1, t + 10);
      STEPF(t + 3, wD0, wD1, 0); LOADW(wD0, wD1, t + 11);
      STEPF(t + 4, wE0, wE1, 0); LOADW(wE0, wE1, t + 12);
      STEPF(t + 5, wF0, wF1, 0); LOADW(wF0, wF1, t + 13);
      STEPF(t + 6, wG0, wG1, 1); LOADW(wG0, wG1, t + 14);
      STEPF(t + 7, wH0, wH1, 0); LOADW(wH0, wH1, t + 15);
    }
    // tail: t = 121..127
    STEPF(121, wA0, wA1, 0); STEPF(122, wB0, wB1, 0); STEPF(123, wC0, wC1, 1);
    STEPF(124, wD0, wD1, 0); STEPF(125, wE0, wE1, 0); STEPF(126, wF0, wF1, 0);
    STEPF(127, wG0, wG1, 0);

    // publish x_127 / scales / snap-dot
#pragma unroll
    for (int k = 0; k < 16; ++k) xs[lane * 16 + k] = y[k];
    Lxs[lane] = Lint;
    float sd = 0.f;
#pragma unroll
    for (int k = 0; k < 16; ++k) sd += snap[k] * eend[k];
    sd += __shfl_xor(sd, 16);
    sd += __shfl_xor(sd, 32);
    if (lane < 16) { s0d[lane] = sd; Ls0[lane] = Lsnap; }

    // gold partial: t in [0,128)
    for (int c = 0; c < 32; ++c) {
      const int tt = q + 4 * c;
      if (tt < len) {
        const int tg = tags[(size_t)tt * B_DIM + b];
        float v = goldRaw[(size_t)tt * B_DIM + b];
        v += (tt == 0) ? beginT[tg]
                       : trans[(size_t)tg * K_DIM + tags[(size_t)(tt - 1) * B_DIM + b]];
        if (tt == cap) v += endT[tg];
        g0 += v;
      }
    }
    float gr = g0;
#pragma unroll
    for (int o = 1; o < 64; o <<= 1) gr += __shfl_xor(gr, o);
    if (lane == 0) gpart = gr;
  } else {
    // ---- backward wave ----
    bfrag_t aET[8];
#pragma unroll
    for (int jt = 0; jt < 4; ++jt)
#pragma unroll
      for (int kt = 0; kt < 2; ++kt) {
        union { bfrag_t v; __hip_bfloat16 h[8]; } u;
#pragma unroll
        for (int r = 0; r < 8; ++r) {
          const int i = (2 * kt + (r >> 2)) * 16 + q * 4 + (r & 3);
          u.h[r] = __float2bfloat16(__expf(trans[(size_t)i * K_DIM + (jt * 16 + n)]));
        }
        aET[jt * 2 + kt] = u.v;
      }

#pragma unroll
    for (int k = 0; k < 16; ++k) y[k] = 0.f;
    LOADW(wA0, wA1, 255); LOADW(wB0, wB1, 254); LOADW(wC0, wC1, 253); LOADW(wD0, wD1, 252);
    LOADW(wE0, wE1, 251); LOADW(wF0, wF1, 250); LOADW(wG0, wG1, 249); LOADW(wH0, wH1, 248);

#define STEPB(T, W0, W1, RSC) { \
    float _w[16]; \
    CVT16(_w, W0, W1); \
    const bool _hit = ((T) == cap); \
    float _d[16]; \
    _Pragma("unroll") for (int k = 0; k < 16; ++k) \
      _d[k] = (_hit ? eend[k] : y[k]) * _w[k]; \
    BUILDBV(_d); \
    f4_t _a0 = __builtin_amdgcn_mfma_f32_16x16x32_bf16(aET[0], bf0, zro, 0, 0, 0); \
    f4_t _a1 = __builtin_amdgcn_mfma_f32_16x16x32_bf16(aET[2], bf0, zro, 0, 0, 0); \
    f4_t _a2 = __builtin_amdgcn_mfma_f32_16x16x32_bf16(aET[4], bf0, zro, 0, 0, 0); \
    f4_t _a3 = __builtin_amdgcn_mfma_f32_16x16x32_bf16(aET[6], bf0, zro, 0, 0, 0); \
    _a0 = __builtin_amdgcn_mfma_f32_16x16x32_bf16(aET[1], bf1, _a0, 0, 0, 0); \
    _a1 = __builtin_amdgcn_mfma_f32_16x16x32_bf16(aET[3], bf1, _a1, 0, 0, 0); \
    _a2 = __builtin_amdgcn_mfma_f32_16x16x32_bf16(aET[5], bf1, _a2, 0, 0, 0); \
    _a3 = __builtin_amdgcn_mfma_f32_16x16x32_bf16(aET[7], bf1, _a3, 0, 0, 0); \
    _Pragma("unroll") for (int r = 0; r < 4; ++r) { \
      y[r]      = _a0[r]; \
      y[4 + r]  = _a1[r]; \
      y[8 + r]  = _a2[r]; \
      y[12 + r] = _a3[r]; } \
    if (RSC) { RESCALE(); } }

    int t = 255;
    for (int it = 0; it < 16; ++it, t -= 8) {
      STEPB(t - 0, wA0, wA1, 0); LOADW(wA0, wA1, t - 8);
      STEPB(t - 1, wB0, wB1, 0); LOADW(wB0, wB1, t - 9);
      STEPB(t - 2, wC0, wC1, 1); LOADW(wC0, wC1, t - 10);
      STEPB(t - 3, wD0, wD1, 0); LOADW(wD0, wD1, t - 11);
      STEPB(t - 4, wE0, wE1, 0); LOADW(wE0, wE1, t - 12);
      STEPB(t - 5, wF0, wF1, 0); LOADW(wF0, wF1, t - 13);
      STEPB(t - 6, wG0, wG1, 1); LOADW(wG0, wG1, t - 14);
      STEPB(t - 7, wH0, wH1, 0); LOADW(wH0, wH1, t - 15);
    }
    // y = u_127 (scale Lint = Lu)

    // gold partial: t in [128,256)
    for (int c = 0; c < 32; ++c) {
      const int tt = 128 + q + 4 * c;
      if (tt < len) {
        const int tg = tags[(size_t)tt * B_DIM + b];
        float v = goldRaw[(size_t)tt * B_DIM + b];
        v += trans[(size_t)tg * K_DIM + tags[(size_t)(tt - 1) * B_DIM + b]];
        if (tt == cap) v += endT[tg];
        g0 += v;
      }
    }
  }

  __syncthreads();

  if (wv == 1) {
    float dot1 = 0.f;
#pragma unroll
    for (int k = 0; k < 16; ++k) dot1 += xs[lane * 16 + k] * y[k];
    dot1 += __shfl_xor(dot1, 16);
    dot1 += __shfl_xor(dot1, 32);

    const bool hi = (cap >= 128);
    const float dsel = hi ? dot1 : s0d[n];
    const float Lsel = (float)(hi ? (Lxs[lane] + Lint) : Ls0[n]);
    const float f = __logf(dsel) + Lsel * LN2F;

    float r = 0.25f * f - g0;
#pragma unroll
    for (int o = 1; o < 64; o <<= 1) r += __shfl_xor(r, o);
    if (lane == 0) atomicAdd(out, r - gpart);
  }
}

// ---------------------------------------------------------------------------
extern "C" void kernel_launch(void* const* d_in, const int* in_sizes, int n_in,
                              void* d_out, int out_size, void* d_ws, size_t ws_size,
                              hipStream_t stream) {
  const float* hiddens = (const float*)d_in[0];  // [T,B,H]
  const int*   lens    = (const int*)  d_in[1];  // [B]
  const int*   tags    = (const int*)  d_in[2];  // [T,B]
  const float* W       = (const float*)d_in[3];  // [K,H]
  const float* bias    = (const float*)d_in[4];  // [K]
  const float* beginT  = (const float*)d_in[5];  // [K]
  const float* trans   = (const float*)d_in[6];  // [K,K]
  const float* endT    = (const float*)d_in[7];  // [K]

  short* emPb    = (short*)d_ws;                            // 8.4 MB bf16
  float* goldRaw = (float*)(emPb + (size_t)16 * 256 * 64 * 16);  // 256 KB
  short* Wb      = (short*)(goldRaw + B_DIM * T_DIM);       // 64 KB bf16
  float* out     = (float*)d_out;

  wconv<<<(K_DIM * H_DIM) / (256 * 8), 256, 0, stream>>>(W, Wb, out);
  emis_gemm10<<<(T_DIM * B_DIM) / 64, 256, 0, stream>>>(hiddens, Wb, bias, tags, emPb, goldRaw);
  crf_dp10<<<16, 128, 0, stream>>>(emPb, goldRaw, lens, tags, trans, beginT, endT, out);
}